// Round 4
// baseline (894.291 us; speedup 1.0000x reference)
//
#include <hip/hip_runtime.h>
#include <stdint.h>
#include <stddef.h>

// MLA prefill: B=2,S=2048,D=2048,H=16,DH=128,DR=64,DCKV=512,DCQ=1536
#define BB 2
#define SS 2048
#define DD 2048
#define HH 16
#define DHH 128
#define DRR 64
#define DCKV 512
#define DCQ 1536

typedef __attribute__((ext_vector_type(8))) short short8;
typedef __attribute__((ext_vector_type(4))) short short4v;
typedef __attribute__((ext_vector_type(4))) float f32x4;

__device__ __forceinline__ short f2bf(float x) {
  unsigned u = __float_as_uint(x);
  u += 0x7fffu + ((u >> 16) & 1u);   // RNE
  return (short)(u >> 16);
}
__device__ __forceinline__ float bf2f(short s) {
  return __uint_as_float(((unsigned)(unsigned short)s) << 16);
}

// ---------------- cast fp32 -> bf16, x4 vectorized ----------------
__global__ __launch_bounds__(256) void cast_bf16_kernel(const float* __restrict__ in,
                                                        short* __restrict__ out, int n4) {
  int i = blockIdx.x * 256 + threadIdx.x;
  if (i >= n4) return;
  f32x4 f = ((const f32x4*)in)[i];
  short4v o;
  o[0] = f2bf(f[0]); o[1] = f2bf(f[1]); o[2] = f2bf(f[2]); o[3] = f2bf(f[3]);
  ((short4v*)out)[i] = o;
}

// ---------------- concat biases into cb1[3072], cb2[3072], cb3[4096] ----------------
__global__ __launch_bounds__(256) void concat_bias_kernel(
    const float* bkd, const float* bqd, const float* bkr,
    const float* bqu, const float* bqr, const float* bku, const float* bvu,
    float* cb1, float* cb2, float* cb3) {
  int idx = blockIdx.x * 256 + threadIdx.x;
  if (idx < 3072) {
    cb1[idx] = idx < 512 ? bkd[idx] : (idx < 2048 ? bqd[idx - 512] : bkr[idx - 2048]);
  } else if (idx < 6144) {
    int j = idx - 3072;
    cb2[j] = j < 2048 ? bqu[j] : bqr[j - 2048];
  } else if (idx < 10240) {
    int j = idx - 6144;
    cb3[j] = j < 2048 ? bku[j] : bvu[j - 2048];
  }
}

// ---------------- C[M,N] = A[M,K] @ B[N,K]^T + bias ----------------
// Register-staged LDS (R1-proven), 128x128 tile, BK=32, 4 waves.
// LDS XOR-swizzle: slot(row,q) = row*4 + (q ^ ((row>>1)&3)) -> conflict-free b128 reads.
// MODE 0: bf16 row-major -> Cout(N).  MODE 1: f32 row-major -> Cout(N).
// MODE 2: col<2048 scatter to qfull[B,H,S,192]; col>=2048 -> out2[row*1024+col-2048].
// MODE 3: col<2048 scatter to kfull[B,H,S,192]; col>=2048 -> out2[row*2048+col-2048].
template<int MODE>
__global__ __launch_bounds__(256) void gemm_bt(const short* __restrict__ A, int lda,
                                               const short* __restrict__ Bm, int ldb,
                                               const float* __restrict__ bias,
                                               void* __restrict__ Cout, void* __restrict__ out2,
                                               int M, int N, int K) {
  __shared__ short sA[128 * 32];
  __shared__ short sB[128 * 32];
  const int tid = threadIdx.x;
  const int w = tid >> 6, L = tid & 63, quad = L >> 4, lc = L & 15;
  const int wm = w >> 1, wn = w & 1;
  const int tm = blockIdx.x * 128, tn = blockIdx.y * 128;
  f32x4 acc[4][4] = {};
  const int nk = K >> 5;
  for (int kt = 0; kt < nk; ++kt) {
    const int k0 = kt << 5;
    __syncthreads();
#pragma unroll
    for (int i = 0; i < 2; ++i) {
      int g = i * 256 + tid;
      int r = g >> 2, q = g & 3;
      int slot = (g & ~3) | (q ^ ((r >> 1) & 3));
      short8 va = *(const short8*)(A + (size_t)(tm + r) * lda + k0 + q * 8);
      *(short8*)&sA[slot * 8] = va;
      short8 vb = *(const short8*)(Bm + (size_t)(tn + r) * ldb + k0 + q * 8);
      *(short8*)&sB[slot * 8] = vb;
    }
    __syncthreads();
    short8 af[4], bfr[4];
#pragma unroll
    for (int ms = 0; ms < 4; ++ms) {
      int rr = wm * 64 + ms * 16 + lc;
      af[ms] = *(const short8*)&sA[(rr * 4 + (quad ^ ((rr >> 1) & 3))) * 8];
    }
#pragma unroll
    for (int ns = 0; ns < 4; ++ns) {
      int rr = wn * 64 + ns * 16 + lc;
      bfr[ns] = *(const short8*)&sB[(rr * 4 + (quad ^ ((rr >> 1) & 3))) * 8];
    }
#pragma unroll
    for (int ms = 0; ms < 4; ++ms)
#pragma unroll
      for (int ns = 0; ns < 4; ++ns)
        acc[ms][ns] = __builtin_amdgcn_mfma_f32_16x16x32_bf16(af[ms], bfr[ns], acc[ms][ns], 0, 0, 0);
  }
  // epilogue: C row = quad*4+reg, col = lane&15 (verified m89/m91 layout)
#pragma unroll
  for (int ms = 0; ms < 4; ++ms) {
    int row = tm + wm * 64 + ms * 16 + quad * 4;
#pragma unroll
    for (int ns = 0; ns < 4; ++ns) {
      int col = tn + wn * 64 + ns * 16 + lc;
      float bv = bias[col];
#pragma unroll
      for (int r = 0; r < 4; ++r) {
        float vv = acc[ms][ns][r] + bv;
        int rrow = row + r;
        if (MODE == 0)      ((short*)Cout)[(size_t)rrow * N + col] = f2bf(vv);
        else if (MODE == 1) ((float*)Cout)[(size_t)rrow * N + col] = vv;
        else {
          if (col < 2048) {  // content -> full[B,H,S,192] (block-uniform branch)
            int b_ = rrow >> 11, s_ = rrow & 2047, h_ = col >> 7, d_ = col & 127;
            ((short*)Cout)[(((size_t)(b_ * HH + h_)) * SS + s_) * 192 + d_] = f2bf(vv);
          } else {
            int auxn = (MODE == 2) ? 1024 : 2048;
            ((short*)out2)[(size_t)rrow * auxn + (col - 2048)] = f2bf(vv);
          }
        }
      }
    }
  }
}

// ------------- RoPE (rotate-half) into full[...,128:192]; strided bf16 src -------------
__global__ __launch_bounds__(256) void rope_kernel(const short* __restrict__ rin,
                                                   int rstride, int roff,
                                                   short* __restrict__ full) {
  int idx = blockIdx.x * 256 + threadIdx.x;  // B*S*H*32 threads
  int i = idx & 31, h = (idx >> 5) & 15, s = (idx >> 9) & 2047, b = idx >> 20;
  const short* base = rin + ((size_t)(b * SS + s)) * rstride + roff + h * DRR;
  float t1 = bf2f(base[i]), t2 = bf2f(base[i + 32]);
  float invf = expf(-9.210340371976184f * (float)i * (1.0f / 32.0f));  // 10000^(-i/32)
  float ang = (float)s * invf;
  float c = cosf(ang), sn = sinf(ang);
  short* ob = full + (((size_t)(b * HH + h)) * SS + s) * 192 + 128;
  ob[i]      = f2bf(t1 * c - t2 * sn);
  ob[i + 32] = f2bf(t1 * sn + t2 * c);
}

// ------------- V [B,S,H*DH] -> Vt [B,H,DH,S] -------------
__global__ __launch_bounds__(256) void transpose_v_kernel(const short* __restrict__ v,
                                                          short* __restrict__ vt) {
  int idx = blockIdx.x * 256 + threadIdx.x;  // B*H*DH*S threads
  int s = idx & 2047, d = (idx >> 11) & 127, h = (idx >> 18) & 15, b = idx >> 22;
  vt[idx] = v[((size_t)(b * SS + s)) * 2048 + h * 128 + d];
}

__device__ __forceinline__ float quad_max(float v) {
  v = fmaxf(v, __shfl_xor(v, 1));
  v = fmaxf(v, __shfl_xor(v, 2));
  v = fmaxf(v, __shfl_xor(v, 4));
  v = fmaxf(v, __shfl_xor(v, 8));
  return v;
}
__device__ __forceinline__ float quad_sum(float v) {
  v += __shfl_xor(v, 1); v += __shfl_xor(v, 2);
  v += __shfl_xor(v, 4); v += __shfl_xor(v, 8);
  return v;
}

// ------------- flash attention, 2-way split-K -------------
// grid (32, B*H): bx -> (qt = 15 - bx/2, sp = bx&1). Split sp covers kt range
// [0,half) or [half,qt+1). Outputs UNNORMALIZED O (fp32) + (m,l) partials.
// K-tile staged into 48KB LDS (XOR swizzle); P (128x136) unioned over sK.
// 3 barriers/iter (P rows wave-private -> no post-P-write barrier).
__global__ __launch_bounds__(256, 3) void mla_flash_kernel(const short* __restrict__ Qf,
                                                           const short* __restrict__ Kf,
                                                           const short* __restrict__ Vt,
                                                           float* __restrict__ Op,
                                                           float2* __restrict__ ml) {
  const int qt = 15 - (int)(blockIdx.x >> 1);  // heavy blocks dispatch first
  const int sp = blockIdx.x & 1;
  const int bh = blockIdx.y, h = bh & 15, b = bh >> 4;
  const int tid = threadIdx.x, w = tid >> 6, L = tid & 63, quad = L >> 4, lc = L & 15;
  __shared__ __align__(16) short sK[6 * 128 * 32];  // 48KB; P unioned at offset 0
  short* Pf = sK;                                   // [128][136] bf16

  const int nkt = qt + 1, half = (nkt + 1) >> 1;
  const int kt0 = sp ? half : 0, kt1 = sp ? nkt : half;

  const short* Qb = Qf + ((size_t)bh) * SS * 192;
  const short* Kb = Kf + ((size_t)bh) * SS * 192;
  const short* Vb = Vt + ((size_t)bh) * DHH * SS;

  const int qrow0 = qt * 128 + w * 32;
  short8 qa[2][6];
#pragma unroll
  for (int ms = 0; ms < 2; ++ms)
#pragma unroll
    for (int kk = 0; kk < 6; ++kk)
      qa[ms][kk] = *(const short8*)(Qb + (size_t)(qrow0 + ms * 16 + lc) * 192 + kk * 32 + quad * 8);

  f32x4 O[2][8] = {};
  float mrow[2][4], lrow[2][4];
#pragma unroll
  for (int ms = 0; ms < 2; ++ms)
#pragma unroll
    for (int r = 0; r < 4; ++r) { mrow[ms][r] = -1e30f; lrow[ms][r] = 0.f; }

  for (int kt = kt0; kt < kt1; ++kt) {
    __syncthreads();  // prior iter's P/sK LDS reads all done before overwrite
    // stage K-tile [kt*128, +128) x 192 into sK: 3072 16B chunks, 12/thread
#pragma unroll
    for (int i = 0; i < 12; ++i) {
      int idx = i * 256 + tid;
      int seg = idx >> 9, rem = idx & 511, row = rem >> 2, q = rem & 3;
      short8 v = *(const short8*)(Kb + (size_t)(kt * 128 + row) * 192 + seg * 32 + q * 8);
      int slot = row * 4 + (q ^ ((row >> 1) & 3));
      *(short8*)&sK[(seg * 512 + slot) * 8] = v;
    }
    __syncthreads();  // sK ready
    f32x4 sc[2][8] = {};
#pragma unroll
    for (int kk = 0; kk < 6; ++kk)
#pragma unroll
      for (int ns = 0; ns < 8; ++ns) {
        int rr = ns * 16 + lc;
        short8 kb = *(const short8*)&sK[(kk * 512 + rr * 4 + (quad ^ ((rr >> 1) & 3))) * 8];
        sc[0][ns] = __builtin_amdgcn_mfma_f32_16x16x32_bf16(qa[0][kk], kb, sc[0][ns], 0, 0, 0);
        sc[1][ns] = __builtin_amdgcn_mfma_f32_16x16x32_bf16(qa[1][kk], kb, sc[1][ns], 0, 0, 0);
      }
    const float scale = 0.07216878364870322f;  // 1/sqrt(192)
    const bool diag = (kt == qt);
#pragma unroll
    for (int ms = 0; ms < 2; ++ms)
#pragma unroll
      for (int ns = 0; ns < 8; ++ns)
#pragma unroll
        for (int r = 0; r < 4; ++r) {
          float vv = sc[ms][ns][r] * scale;
          if (diag && (ns * 16 + lc > w * 32 + ms * 16 + quad * 4 + r)) vv = -1e30f;
          sc[ms][ns][r] = vv;
        }
    // online softmax; row (ms, quad*4+r) lives in this quad's 16 lanes
#pragma unroll
    for (int ms = 0; ms < 2; ++ms)
#pragma unroll
      for (int r = 0; r < 4; ++r) {
        float mx = sc[ms][0][r];
#pragma unroll
        for (int ns = 1; ns < 8; ++ns) mx = fmaxf(mx, sc[ms][ns][r]);
        mx = quad_max(mx);
        float mnew = fmaxf(mrow[ms][r], mx);
        float alpha = __expf(mrow[ms][r] - mnew);
        mrow[ms][r] = mnew;
        float ps = 0.f;
#pragma unroll
        for (int ns = 0; ns < 8; ++ns) {
          float p = __expf(sc[ms][ns][r] - mnew);
          sc[ms][ns][r] = p;
          ps += p;
        }
        ps = quad_sum(ps);
        lrow[ms][r] = lrow[ms][r] * alpha + ps;
#pragma unroll
        for (int n = 0; n < 8; ++n) O[ms][n][r] *= alpha;
      }
    __syncthreads();  // all waves' QK sK-reads done before P overwrites region
    // P (bf16) C-layout -> LDS (wave-private rows; same-wave RAW via lgkmcnt)
#pragma unroll
    for (int ms = 0; ms < 2; ++ms)
#pragma unroll
      for (int ns = 0; ns < 8; ++ns)
#pragma unroll
        for (int r = 0; r < 4; ++r)
          Pf[(w * 32 + ms * 16 + quad * 4 + r) * 136 + ns * 16 + lc] = f2bf(sc[ms][ns][r]);
    // PV: A = P (own rows, A-layout), B = Vt
#pragma unroll
    for (int kk2 = 0; kk2 < 4; ++kk2) {
      short8 pa[2];
      pa[0] = *(const short8*)&Pf[(w * 32 + lc) * 136 + kk2 * 32 + quad * 8];
      pa[1] = *(const short8*)&Pf[(w * 32 + 16 + lc) * 136 + kk2 * 32 + quad * 8];
      short8 vb[8];
#pragma unroll
      for (int n = 0; n < 8; ++n)
        vb[n] = *(const short8*)(Vb + (size_t)(n * 16 + lc) * SS + kt * 128 + kk2 * 32 + quad * 8);
#pragma unroll
      for (int ms = 0; ms < 2; ++ms)
#pragma unroll
        for (int n = 0; n < 8; ++n)
          O[ms][n] = __builtin_amdgcn_mfma_f32_16x16x32_bf16(pa[ms], vb[n], O[ms][n], 0, 0, 0);
    }
  }
  // epilogue: store unnormalized O partial (fp32) + (m,l) per row
  const size_t spO = (size_t)sp * (65536u * 128u);
  const int spM = sp * 65536;
#pragma unroll
  for (int ms = 0; ms < 2; ++ms)
#pragma unroll
    for (int r = 0; r < 4; ++r) {
      int srow = qt * 128 + w * 32 + ms * 16 + quad * 4 + r;
      size_t rq = (size_t)bh * SS + srow;
      float* dst = Op + spO + rq * 128;
#pragma unroll
      for (int n = 0; n < 8; ++n)
        dst[n * 16 + lc] = O[ms][n][r];
      if (lc == 0) ml[spM + rq] = make_float2(mrow[ms][r], lrow[ms][r]);
    }
}

// ------------- combine 2 split-K partials -> attn bf16 [B,S,H*DH] -------------
__global__ __launch_bounds__(256) void combine_kernel(const float* __restrict__ Op,
                                                      const float2* __restrict__ ml,
                                                      short* __restrict__ attn) {
  int idx = blockIdx.x * 256 + threadIdx.x;  // 65536 rows x 32 f32x4 groups
  int d4 = idx & 31;
  size_t rq = (size_t)(idx >> 5);
  float2 p1 = ml[rq], p2 = ml[65536 + rq];
  float m = fmaxf(p1.x, p2.x);
  float e1 = __expf(p1.x - m), e2 = __expf(p2.x - m);
  float inv = 1.0f / (p1.y * e1 + p2.y * e2);
  f32x4 o1 = *(const f32x4*)(Op + rq * 128 + d4 * 4);
  f32x4 o2 = *(const f32x4*)(Op + (size_t)65536 * 128 + rq * 128 + d4 * 4);
  int bh = (int)(rq >> 11), s = (int)(rq & 2047), b = bh >> 4, h = bh & 15;
  short4v o;
#pragma unroll
  for (int j = 0; j < 4; ++j) o[j] = f2bf((o1[j] * e1 + o2[j] * e2) * inv);
  *(short4v*)(attn + ((size_t)(b * SS + s)) * 2048 + h * 128 + d4 * 4) = o;
}

extern "C" void kernel_launch(void* const* d_in, const int* in_sizes, int n_in,
                              void* d_out, int out_size, void* d_ws, size_t ws_size,
                              hipStream_t stream) {
  const float* x   = (const float*)d_in[0];
  const float* Wkd = (const float*)d_in[1];
  const float* bkd = (const float*)d_in[2];
  const float* Wqd = (const float*)d_in[3];
  const float* bqd = (const float*)d_in[4];
  const float* Wku = (const float*)d_in[5];
  const float* bku = (const float*)d_in[6];
  const float* Wvu = (const float*)d_in[7];
  const float* bvu = (const float*)d_in[8];
  const float* Wqu = (const float*)d_in[9];
  const float* bqu = (const float*)d_in[10];
  const float* Wkr = (const float*)d_in[11];
  const float* bkr = (const float*)d_in[12];
  const float* Wqr = (const float*)d_in[13];
  const float* bqr = (const float*)d_in[14];
  const float* Wo  = (const float*)d_in[15];
  const float* bo  = (const float*)d_in[16];

  char* ws = (char*)d_ws;
  size_t off = 0;
  auto alloc = [&](size_t elems, size_t esz) -> void* {
    void* p = (void*)(ws + off);
    off += elems * esz;
    off = (off + 255) & ~(size_t)255;
    return p;
  };
  const int MS = BB * SS;  // 4096
  // --- alias pool (all consumed before flash): Op overlays these 67,108,864 B ---
  short* xb    = (short*)alloc((size_t)MS * DD, 2);          // 16,777,216 B
  short* cbuf  = (short*)alloc((size_t)MS * 3072, 2);        // 25,165,824 B
  short* qrbuf = (short*)alloc((size_t)MS * 1024, 2);        //  8,388,608 B
  short* vbuf  = (short*)alloc((size_t)MS * 2048, 2);        // 16,777,216 B
  float* Op    = (float*)xb;  // 2 x 65536 x 128 f32 = 67,108,864 B, exact fit
  // --- persistent ---
  short* w1    = (short*)alloc((size_t)3072 * 2048, 2);  // [Wkd;Wqd;Wkr]
  short* w2    = (short*)alloc((size_t)3072 * 1536, 2);  // [Wqu;Wqr]
  short* w3    = (short*)alloc((size_t)4096 * 512, 2);   // [Wku;Wvu]
  short* wob   = (short*)alloc((size_t)2048 * 2048, 2);
  float* cb1   = (float*)alloc(3072, 4);
  float* cb2   = (float*)alloc(3072, 4);
  float* cb3   = (float*)alloc(4096, 4);
  short* qfull = (short*)alloc((size_t)BB * HH * SS * 192, 2);
  short* kfull = (short*)alloc((size_t)BB * HH * SS * 192, 2);
  short* vt    = (short*)alloc((size_t)BB * HH * DHH * SS, 2);
  short* attn  = (short*)alloc((size_t)MS * 2048, 2);
  float2* ml   = (float2*)alloc((size_t)2 * 65536, 8);
  if (off > ws_size) return;  // workspace too small: fail visibly

  auto cast = [&](const float* src, short* dst, size_t n) {
    int n4 = (int)(n >> 2);
    cast_bf16_kernel<<<dim3((unsigned)((n4 + 255) / 256)), dim3(256), 0, stream>>>(src, dst, n4);
  };
  cast(x,   xb, (size_t)MS * DD);
  cast(Wkd, w1,                          (size_t)512 * 2048);
  cast(Wqd, w1 + (size_t)512 * 2048,     (size_t)1536 * 2048);
  cast(Wkr, w1 + (size_t)2048 * 2048,    (size_t)1024 * 2048);
  cast(Wqu, w2,                          (size_t)2048 * 1536);
  cast(Wqr, w2 + (size_t)2048 * 1536,    (size_t)1024 * 1536);
  cast(Wku, w3,                          (size_t)2048 * 512);
  cast(Wvu, w3 + (size_t)2048 * 512,     (size_t)2048 * 512);
  cast(Wo,  wob,                         (size_t)2048 * 2048);
  concat_bias_kernel<<<dim3(40), dim3(256), 0, stream>>>(bkd, bqd, bkr, bqu, bqr, bku, bvu,
                                                         cb1, cb2, cb3);

  dim3 blk(256);
  // GEMM1: x @ [Wkd;Wqd;Wkr]^T -> cbuf [4096 x 3072] (kvc | qc | k_r)
  gemm_bt<0><<<dim3(32, 24), blk, 0, stream>>>(xb, DD, w1, DD, cb1, cbuf, nullptr,
                                               MS, 3072, DD);
  // GEMM2: qc @ [Wqu;Wqr]^T -> q_cnt scattered to qfull + q_r -> qrbuf
  gemm_bt<2><<<dim3(32, 24), blk, 0, stream>>>(cbuf + 512, 3072, w2, DCQ, cb2, qfull, qrbuf,
                                               MS, 3072, DCQ);
  // GEMM3: kvc @ [Wku;Wvu]^T -> k_cnt scattered to kfull + v -> vbuf
  gemm_bt<3><<<dim3(32, 32), blk, 0, stream>>>(cbuf, 3072, w3, DCKV, cb3, kfull, vbuf,
                                               MS, 4096, DCKV);

  rope_kernel<<<dim3(BB * SS * HH * 32 / 256), blk, 0, stream>>>(qrbuf, 1024, 0, qfull);
  rope_kernel<<<dim3(BB * SS * HH * 32 / 256), blk, 0, stream>>>(cbuf, 3072, 2048, kfull);
  transpose_v_kernel<<<dim3(BB * HH * DHH * SS / 256), blk, 0, stream>>>(vbuf, vt);

  mla_flash_kernel<<<dim3(32, BB * HH), blk, 0, stream>>>(qfull, kfull, vt, Op, ml);
  combine_kernel<<<dim3(65536 * 32 / 256), blk, 0, stream>>>(Op, ml, attn);

  gemm_bt<1><<<dim3(32, 16), blk, 0, stream>>>(attn, DD, wob, DD, bo, d_out, nullptr,
                                               MS, DD, DD);
}

// Round 5
// 761.845 us; speedup vs baseline: 1.1738x; 1.1738x over previous
//
#include <hip/hip_runtime.h>
#include <stdint.h>
#include <stddef.h>

// MLA prefill: B=2,S=2048,D=2048,H=16,DH=128,DR=64,DCKV=512,DCQ=1536
#define BB 2
#define SS 2048
#define DD 2048
#define HH 16
#define DHH 128
#define DRR 64
#define DCKV 512
#define DCQ 1536

typedef __attribute__((ext_vector_type(8))) short short8;
typedef __attribute__((ext_vector_type(4))) short short4v;
typedef __attribute__((ext_vector_type(4))) float f32x4;

__device__ __forceinline__ short f2bf(float x) {
  unsigned u = __float_as_uint(x);
  u += 0x7fffu + ((u >> 16) & 1u);   // RNE
  return (short)(u >> 16);
}
__device__ __forceinline__ float bf2f(short s) {
  return __uint_as_float(((unsigned)(unsigned short)s) << 16);
}

// ---------------- cast fp32 -> bf16, x4 vectorized ----------------
__global__ __launch_bounds__(256) void cast_bf16_kernel(const float* __restrict__ in,
                                                        short* __restrict__ out, int n4) {
  int i = blockIdx.x * 256 + threadIdx.x;
  if (i >= n4) return;
  f32x4 f = ((const f32x4*)in)[i];
  short4v o;
  o[0] = f2bf(f[0]); o[1] = f2bf(f[1]); o[2] = f2bf(f[2]); o[3] = f2bf(f[3]);
  ((short4v*)out)[i] = o;
}

// ---------------- concat biases into cb1[3072], cb2[3072], cb3[4096] ----------------
__global__ __launch_bounds__(256) void concat_bias_kernel(
    const float* bkd, const float* bqd, const float* bkr,
    const float* bqu, const float* bqr, const float* bku, const float* bvu,
    float* cb1, float* cb2, float* cb3) {
  int idx = blockIdx.x * 256 + threadIdx.x;
  if (idx < 3072) {
    cb1[idx] = idx < 512 ? bkd[idx] : (idx < 2048 ? bqd[idx - 512] : bkr[idx - 2048]);
  } else if (idx < 6144) {
    int j = idx - 3072;
    cb2[j] = j < 2048 ? bqu[j] : bqr[j - 2048];
  } else if (idx < 10240) {
    int j = idx - 6144;
    cb3[j] = j < 2048 ? bku[j] : bvu[j - 2048];
  }
}

// ---------------- C[M,N] = A[M,K] @ B[N,K]^T + bias ----------------
// Register-staged LDS (R1-proven), 128x128 tile, BK=32, 4 waves.
// LDS XOR-swizzle: slot(row,q) = row*4 + (q ^ ((row>>1)&3)) -> conflict-free b128 reads.
// MODE 0: bf16 row-major -> Cout(N).  MODE 1: f32 row-major -> Cout(N).
// MODE 2: col<2048 scatter to qfull[B,H,S,192]; col>=2048 -> out2[row*1024+col-2048].
// MODE 3: col<2048 scatter to kfull[B,H,S,192]; col>=2048 -> out2[row*2048+col-2048].
template<int MODE>
__global__ __launch_bounds__(256) void gemm_bt(const short* __restrict__ A, int lda,
                                               const short* __restrict__ Bm, int ldb,
                                               const float* __restrict__ bias,
                                               void* __restrict__ Cout, void* __restrict__ out2,
                                               int M, int N, int K) {
  __shared__ short sA[128 * 32];
  __shared__ short sB[128 * 32];
  const int tid = threadIdx.x;
  const int w = tid >> 6, L = tid & 63, quad = L >> 4, lc = L & 15;
  const int wm = w >> 1, wn = w & 1;
  const int tm = blockIdx.x * 128, tn = blockIdx.y * 128;
  f32x4 acc[4][4] = {};
  const int nk = K >> 5;
  for (int kt = 0; kt < nk; ++kt) {
    const int k0 = kt << 5;
    __syncthreads();
#pragma unroll
    for (int i = 0; i < 2; ++i) {
      int g = i * 256 + tid;
      int r = g >> 2, q = g & 3;
      int slot = (g & ~3) | (q ^ ((r >> 1) & 3));
      short8 va = *(const short8*)(A + (size_t)(tm + r) * lda + k0 + q * 8);
      *(short8*)&sA[slot * 8] = va;
      short8 vb = *(const short8*)(Bm + (size_t)(tn + r) * ldb + k0 + q * 8);
      *(short8*)&sB[slot * 8] = vb;
    }
    __syncthreads();
    short8 af[4], bfr[4];
#pragma unroll
    for (int ms = 0; ms < 4; ++ms) {
      int rr = wm * 64 + ms * 16 + lc;
      af[ms] = *(const short8*)&sA[(rr * 4 + (quad ^ ((rr >> 1) & 3))) * 8];
    }
#pragma unroll
    for (int ns = 0; ns < 4; ++ns) {
      int rr = wn * 64 + ns * 16 + lc;
      bfr[ns] = *(const short8*)&sB[(rr * 4 + (quad ^ ((rr >> 1) & 3))) * 8];
    }
#pragma unroll
    for (int ms = 0; ms < 4; ++ms)
#pragma unroll
      for (int ns = 0; ns < 4; ++ns)
        acc[ms][ns] = __builtin_amdgcn_mfma_f32_16x16x32_bf16(af[ms], bfr[ns], acc[ms][ns], 0, 0, 0);
  }
  // epilogue: C row = quad*4+reg, col = lane&15 (verified m89/m91 layout)
#pragma unroll
  for (int ms = 0; ms < 4; ++ms) {
    int row = tm + wm * 64 + ms * 16 + quad * 4;
#pragma unroll
    for (int ns = 0; ns < 4; ++ns) {
      int col = tn + wn * 64 + ns * 16 + lc;
      float bv = bias[col];
#pragma unroll
      for (int r = 0; r < 4; ++r) {
        float vv = acc[ms][ns][r] + bv;
        int rrow = row + r;
        if (MODE == 0)      ((short*)Cout)[(size_t)rrow * N + col] = f2bf(vv);
        else if (MODE == 1) ((float*)Cout)[(size_t)rrow * N + col] = vv;
        else {
          if (col < 2048) {  // content -> full[B,H,S,192] (block-uniform branch)
            int b_ = rrow >> 11, s_ = rrow & 2047, h_ = col >> 7, d_ = col & 127;
            ((short*)Cout)[(((size_t)(b_ * HH + h_)) * SS + s_) * 192 + d_] = f2bf(vv);
          } else {
            int auxn = (MODE == 2) ? 1024 : 2048;
            ((short*)out2)[(size_t)rrow * auxn + (col - 2048)] = f2bf(vv);
          }
        }
      }
    }
  }
}

// ------------- RoPE (rotate-half) into full[...,128:192]; strided bf16 src -------------
__global__ __launch_bounds__(256) void rope_kernel(const short* __restrict__ rin,
                                                   int rstride, int roff,
                                                   short* __restrict__ full) {
  int idx = blockIdx.x * 256 + threadIdx.x;  // B*S*H*32 threads
  int i = idx & 31, h = (idx >> 5) & 15, s = (idx >> 9) & 2047, b = idx >> 20;
  const short* base = rin + ((size_t)(b * SS + s)) * rstride + roff + h * DRR;
  float t1 = bf2f(base[i]), t2 = bf2f(base[i + 32]);
  float invf = expf(-9.210340371976184f * (float)i * (1.0f / 32.0f));  // 10000^(-i/32)
  float ang = (float)s * invf;
  float c = cosf(ang), sn = sinf(ang);
  short* ob = full + (((size_t)(b * HH + h)) * SS + s) * 192 + 128;
  ob[i]      = f2bf(t1 * c - t2 * sn);
  ob[i + 32] = f2bf(t1 * sn + t2 * c);
}

// ------------- V [B,S,H*DH] -> Vt [B,H,DH,S] -------------
__global__ __launch_bounds__(256) void transpose_v_kernel(const short* __restrict__ v,
                                                          short* __restrict__ vt) {
  int idx = blockIdx.x * 256 + threadIdx.x;  // B*H*DH*S threads
  int s = idx & 2047, d = (idx >> 11) & 127, h = (idx >> 18) & 15, b = idx >> 22;
  vt[idx] = v[((size_t)(b * SS + s)) * 2048 + h * 128 + d];
}

__device__ __forceinline__ float quad_max(float v) {
  v = fmaxf(v, __shfl_xor(v, 1));
  v = fmaxf(v, __shfl_xor(v, 2));
  v = fmaxf(v, __shfl_xor(v, 4));
  v = fmaxf(v, __shfl_xor(v, 8));
  return v;
}
__device__ __forceinline__ float quad_sum(float v) {
  v += __shfl_xor(v, 1); v += __shfl_xor(v, 2);
  v += __shfl_xor(v, 4); v += __shfl_xor(v, 8);
  return v;
}

// ------------- flash attention, 2-way split-K, K-prefetch pipelined -------------
// grid (32, B*H): bx -> (qt = 15 - bx/2, sp = bx&1). Outputs UNNORMALIZED O
// (fp32) + (m,l) partials. K-tile staged into 48KB LDS (XOR swizzle) from a
// 12-short8 register prefetch issued the previous iteration (in flight during
// QK+softmax). P (128x136) unioned over sK; 3 barriers/iter.
// NOTE: no min-waves launch_bounds cap beyond 2 — R4's (256,3) forced VGPR=84
// and spilled ~570MB of scratch traffic (FETCH+WRITE blowup, 525us).
__global__ __launch_bounds__(256, 2) void mla_flash_kernel(const short* __restrict__ Qf,
                                                           const short* __restrict__ Kf,
                                                           const short* __restrict__ Vt,
                                                           float* __restrict__ Op,
                                                           float2* __restrict__ ml) {
  const int qt = 15 - (int)(blockIdx.x >> 1);  // heavy blocks dispatch first
  const int sp = blockIdx.x & 1;
  const int bh = blockIdx.y, h = bh & 15, b = bh >> 4;
  const int tid = threadIdx.x, w = tid >> 6, L = tid & 63, quad = L >> 4, lc = L & 15;
  __shared__ __align__(16) short sK[6 * 128 * 32];  // 48KB; P unioned at offset 0
  short* Pf = sK;                                   // [128][136] bf16

  const int nkt = qt + 1, half = (nkt + 1) >> 1;
  const int kt0 = sp ? half : 0, kt1 = sp ? nkt : half;

  const short* Qb = Qf + ((size_t)bh) * SS * 192;
  const short* Kb = Kf + ((size_t)bh) * SS * 192;
  const short* Vb = Vt + ((size_t)bh) * DHH * SS;

  const int qrow0 = qt * 128 + w * 32;
  short8 qa[2][6];
#pragma unroll
  for (int ms = 0; ms < 2; ++ms)
#pragma unroll
    for (int kk = 0; kk < 6; ++kk)
      qa[ms][kk] = *(const short8*)(Qb + (size_t)(qrow0 + ms * 16 + lc) * 192 + kk * 32 + quad * 8);

  f32x4 O[2][8] = {};
  float mrow[2][4], lrow[2][4];
#pragma unroll
  for (int ms = 0; ms < 2; ++ms)
#pragma unroll
    for (int r = 0; r < 4; ++r) { mrow[ms][r] = -1e30f; lrow[ms][r] = 0.f; }

  short8 pf[12];
  // prologue: prefetch first K-tile into registers
  if (kt0 < kt1) {
#pragma unroll
    for (int i = 0; i < 12; ++i) {
      int idx = i * 256 + tid;
      int seg = idx >> 9, rem = idx & 511, row = rem >> 2, q = rem & 3;
      pf[i] = *(const short8*)(Kb + (size_t)(kt0 * 128 + row) * 192 + seg * 32 + q * 8);
    }
  }

  for (int kt = kt0; kt < kt1; ++kt) {
    __syncthreads();  // A: prior iter's sK/Pf LDS reads done before overwrite
    // commit prefetched tile to LDS
#pragma unroll
    for (int i = 0; i < 12; ++i) {
      int idx = i * 256 + tid;
      int seg = idx >> 9, rem = idx & 511, row = rem >> 2, q = rem & 3;
      int slot = row * 4 + (q ^ ((row >> 1) & 3));
      *(short8*)&sK[(seg * 512 + slot) * 8] = pf[i];
    }
    __syncthreads();  // B: sK ready
    // issue next tile's prefetch now: in flight during QK + softmax
    if (kt + 1 < kt1) {
#pragma unroll
      for (int i = 0; i < 12; ++i) {
        int idx = i * 256 + tid;
        int seg = idx >> 9, rem = idx & 511, row = rem >> 2, q = rem & 3;
        pf[i] = *(const short8*)(Kb + (size_t)((kt + 1) * 128 + row) * 192 + seg * 32 + q * 8);
      }
    }
    f32x4 sc[2][8] = {};
#pragma unroll
    for (int kk = 0; kk < 6; ++kk)
#pragma unroll
      for (int ns = 0; ns < 8; ++ns) {
        int rr = ns * 16 + lc;
        short8 kb = *(const short8*)&sK[(kk * 512 + rr * 4 + (quad ^ ((rr >> 1) & 3))) * 8];
        sc[0][ns] = __builtin_amdgcn_mfma_f32_16x16x32_bf16(qa[0][kk], kb, sc[0][ns], 0, 0, 0);
        sc[1][ns] = __builtin_amdgcn_mfma_f32_16x16x32_bf16(qa[1][kk], kb, sc[1][ns], 0, 0, 0);
      }
    const float scale = 0.07216878364870322f;  // 1/sqrt(192)
    const bool diag = (kt == qt);
#pragma unroll
    for (int ms = 0; ms < 2; ++ms)
#pragma unroll
      for (int ns = 0; ns < 8; ++ns)
#pragma unroll
        for (int r = 0; r < 4; ++r) {
          float vv = sc[ms][ns][r] * scale;
          if (diag && (ns * 16 + lc > w * 32 + ms * 16 + quad * 4 + r)) vv = -1e30f;
          sc[ms][ns][r] = vv;
        }
    // online softmax; row (ms, quad*4+r) lives in this quad's 16 lanes
#pragma unroll
    for (int ms = 0; ms < 2; ++ms)
#pragma unroll
      for (int r = 0; r < 4; ++r) {
        float mx = sc[ms][0][r];
#pragma unroll
        for (int ns = 1; ns < 8; ++ns) mx = fmaxf(mx, sc[ms][ns][r]);
        mx = quad_max(mx);
        float mnew = fmaxf(mrow[ms][r], mx);
        float alpha = __expf(mrow[ms][r] - mnew);
        mrow[ms][r] = mnew;
        float ps = 0.f;
#pragma unroll
        for (int ns = 0; ns < 8; ++ns) {
          float p = __expf(sc[ms][ns][r] - mnew);
          sc[ms][ns][r] = p;
          ps += p;
        }
        ps = quad_sum(ps);
        lrow[ms][r] = lrow[ms][r] * alpha + ps;
#pragma unroll
        for (int n = 0; n < 8; ++n) O[ms][n][r] *= alpha;
      }
    __syncthreads();  // C: all waves' QK sK-reads done before P overwrites region
    // P (bf16) C-layout -> LDS (wave-private rows; same-wave RAW via lgkmcnt)
#pragma unroll
    for (int ms = 0; ms < 2; ++ms)
#pragma unroll
      for (int ns = 0; ns < 8; ++ns)
#pragma unroll
        for (int r = 0; r < 4; ++r)
          Pf[(w * 32 + ms * 16 + quad * 4 + r) * 136 + ns * 16 + lc] = f2bf(sc[ms][ns][r]);
    // PV: A = P (own rows, A-layout), B = Vt
#pragma unroll
    for (int kk2 = 0; kk2 < 4; ++kk2) {
      short8 pa[2];
      pa[0] = *(const short8*)&Pf[(w * 32 + lc) * 136 + kk2 * 32 + quad * 8];
      pa[1] = *(const short8*)&Pf[(w * 32 + 16 + lc) * 136 + kk2 * 32 + quad * 8];
      short8 vb[8];
#pragma unroll
      for (int n = 0; n < 8; ++n)
        vb[n] = *(const short8*)(Vb + (size_t)(n * 16 + lc) * SS + kt * 128 + kk2 * 32 + quad * 8);
#pragma unroll
      for (int ms = 0; ms < 2; ++ms)
#pragma unroll
        for (int n = 0; n < 8; ++n)
          O[ms][n] = __builtin_amdgcn_mfma_f32_16x16x32_bf16(pa[ms], vb[n], O[ms][n], 0, 0, 0);
    }
  }
  // epilogue: store unnormalized O partial (fp32) + (m,l) per row
  const size_t spO = (size_t)sp * (65536u * 128u);
  const int spM = sp * 65536;
#pragma unroll
  for (int ms = 0; ms < 2; ++ms)
#pragma unroll
    for (int r = 0; r < 4; ++r) {
      int srow = qt * 128 + w * 32 + ms * 16 + quad * 4 + r;
      size_t rq = (size_t)bh * SS + srow;
      float* dst = Op + spO + rq * 128;
#pragma unroll
      for (int n = 0; n < 8; ++n)
        dst[n * 16 + lc] = O[ms][n][r];
      if (lc == 0) ml[spM + rq] = make_float2(mrow[ms][r], lrow[ms][r]);
    }
}

// ------------- combine 2 split-K partials -> attn bf16 [B,S,H*DH] -------------
__global__ __launch_bounds__(256) void combine_kernel(const float* __restrict__ Op,
                                                      const float2* __restrict__ ml,
                                                      short* __restrict__ attn) {
  int idx = blockIdx.x * 256 + threadIdx.x;  // 65536 rows x 32 f32x4 groups
  int d4 = idx & 31;
  size_t rq = (size_t)(idx >> 5);
  float2 p1 = ml[rq], p2 = ml[65536 + rq];
  float m = fmaxf(p1.x, p2.x);
  float e1 = __expf(p1.x - m), e2 = __expf(p2.x - m);
  float inv = 1.0f / (p1.y * e1 + p2.y * e2);
  f32x4 o1 = *(const f32x4*)(Op + rq * 128 + d4 * 4);
  f32x4 o2 = *(const f32x4*)(Op + (size_t)65536 * 128 + rq * 128 + d4 * 4);
  int bh = (int)(rq >> 11), s = (int)(rq & 2047), b = bh >> 4, h = bh & 15;
  short4v o;
#pragma unroll
  for (int j = 0; j < 4; ++j) o[j] = f2bf((o1[j] * e1 + o2[j] * e2) * inv);
  *(short4v*)(attn + ((size_t)(b * SS + s)) * 2048 + h * 128 + d4 * 4) = o;
}

extern "C" void kernel_launch(void* const* d_in, const int* in_sizes, int n_in,
                              void* d_out, int out_size, void* d_ws, size_t ws_size,
                              hipStream_t stream) {
  const float* x   = (const float*)d_in[0];
  const float* Wkd = (const float*)d_in[1];
  const float* bkd = (const float*)d_in[2];
  const float* Wqd = (const float*)d_in[3];
  const float* bqd = (const float*)d_in[4];
  const float* Wku = (const float*)d_in[5];
  const float* bku = (const float*)d_in[6];
  const float* Wvu = (const float*)d_in[7];
  const float* bvu = (const float*)d_in[8];
  const float* Wqu = (const float*)d_in[9];
  const float* bqu = (const float*)d_in[10];
  const float* Wkr = (const float*)d_in[11];
  const float* bkr = (const float*)d_in[12];
  const float* Wqr = (const float*)d_in[13];
  const float* bqr = (const float*)d_in[14];
  const float* Wo  = (const float*)d_in[15];
  const float* bo  = (const float*)d_in[16];

  char* ws = (char*)d_ws;
  size_t off = 0;
  auto alloc = [&](size_t elems, size_t esz) -> void* {
    void* p = (void*)(ws + off);
    off += elems * esz;
    off = (off + 255) & ~(size_t)255;
    return p;
  };
  const int MS = BB * SS;  // 4096
  // --- alias pool (all consumed before flash): Op overlays these 67,108,864 B ---
  short* xb    = (short*)alloc((size_t)MS * DD, 2);          // 16,777,216 B
  short* cbuf  = (short*)alloc((size_t)MS * 3072, 2);        // 25,165,824 B
  short* qrbuf = (short*)alloc((size_t)MS * 1024, 2);        //  8,388,608 B
  short* vbuf  = (short*)alloc((size_t)MS * 2048, 2);        // 16,777,216 B
  float* Op    = (float*)xb;  // 2 x 65536 x 128 f32 = 67,108,864 B, exact fit
  // --- persistent ---
  short* w1    = (short*)alloc((size_t)3072 * 2048, 2);  // [Wkd;Wqd;Wkr]
  short* w2    = (short*)alloc((size_t)3072 * 1536, 2);  // [Wqu;Wqr]
  short* w3    = (short*)alloc((size_t)4096 * 512, 2);   // [Wku;Wvu]
  short* wob   = (short*)alloc((size_t)2048 * 2048, 2);
  float* cb1   = (float*)alloc(3072, 4);
  float* cb2   = (float*)alloc(3072, 4);
  float* cb3   = (float*)alloc(4096, 4);
  short* qfull = (short*)alloc((size_t)BB * HH * SS * 192, 2);
  short* kfull = (short*)alloc((size_t)BB * HH * SS * 192, 2);
  short* vt    = (short*)alloc((size_t)BB * HH * DHH * SS, 2);
  short* attn  = (short*)alloc((size_t)MS * 2048, 2);
  float2* ml   = (float2*)alloc((size_t)2 * 65536, 8);
  if (off > ws_size) return;  // workspace too small: fail visibly

  auto cast = [&](const float* src, short* dst, size_t n) {
    int n4 = (int)(n >> 2);
    cast_bf16_kernel<<<dim3((unsigned)((n4 + 255) / 256)), dim3(256), 0, stream>>>(src, dst, n4);
  };
  cast(x,   xb, (size_t)MS * DD);
  cast(Wkd, w1,                          (size_t)512 * 2048);
  cast(Wqd, w1 + (size_t)512 * 2048,     (size_t)1536 * 2048);
  cast(Wkr, w1 + (size_t)2048 * 2048,    (size_t)1024 * 2048);
  cast(Wqu, w2,                          (size_t)2048 * 1536);
  cast(Wqr, w2 + (size_t)2048 * 1536,    (size_t)1024 * 1536);
  cast(Wku, w3,                          (size_t)2048 * 512);
  cast(Wvu, w3 + (size_t)2048 * 512,     (size_t)2048 * 512);
  cast(Wo,  wob,                         (size_t)2048 * 2048);
  concat_bias_kernel<<<dim3(40), dim3(256), 0, stream>>>(bkd, bqd, bkr, bqu, bqr, bku, bvu,
                                                         cb1, cb2, cb3);

  dim3 blk(256);
  // GEMM1: x @ [Wkd;Wqd;Wkr]^T -> cbuf [4096 x 3072] (kvc | qc | k_r)
  gemm_bt<0><<<dim3(32, 24), blk, 0, stream>>>(xb, DD, w1, DD, cb1, cbuf, nullptr,
                                               MS, 3072, DD);
  // GEMM2: qc @ [Wqu;Wqr]^T -> q_cnt scattered to qfull + q_r -> qrbuf
  gemm_bt<2><<<dim3(32, 24), blk, 0, stream>>>(cbuf + 512, 3072, w2, DCQ, cb2, qfull, qrbuf,
                                               MS, 3072, DCQ);
  // GEMM3: kvc @ [Wku;Wvu]^T -> k_cnt scattered to kfull + v -> vbuf
  gemm_bt<3><<<dim3(32, 32), blk, 0, stream>>>(cbuf, 3072, w3, DCKV, cb3, kfull, vbuf,
                                               MS, 4096, DCKV);

  rope_kernel<<<dim3(BB * SS * HH * 32 / 256), blk, 0, stream>>>(qrbuf, 1024, 0, qfull);
  rope_kernel<<<dim3(BB * SS * HH * 32 / 256), blk, 0, stream>>>(cbuf, 3072, 2048, kfull);
  transpose_v_kernel<<<dim3(BB * HH * DHH * SS / 256), blk, 0, stream>>>(vbuf, vt);

  mla_flash_kernel<<<dim3(32, BB * HH), blk, 0, stream>>>(qfull, kfull, vt, Op, ml);
  combine_kernel<<<dim3(65536 * 32 / 256), blk, 0, stream>>>(Op, ml, attn);

  gemm_bt<1><<<dim3(32, 16), blk, 0, stream>>>(attn, DD, wob, DD, bo, d_out, nullptr,
                                               MS, DD, DD);
}

// Round 6
// 672.459 us; speedup vs baseline: 1.3299x; 1.1329x over previous
//
#include <hip/hip_runtime.h>
#include <stdint.h>
#include <stddef.h>

// MLA prefill: B=2,S=2048,D=2048,H=16,DH=128,DR=64,DCKV=512,DCQ=1536
#define BB 2
#define SS 2048
#define DD 2048
#define HH 16
#define DHH 128
#define DRR 64
#define DCKV 512
#define DCQ 1536

typedef __attribute__((ext_vector_type(8))) short short8;
typedef __attribute__((ext_vector_type(4))) short short4v;
typedef __attribute__((ext_vector_type(4))) float f32x4;
typedef unsigned int u32;

__device__ __forceinline__ short f2bf(float x) {
  unsigned u = __float_as_uint(x);
  u += 0x7fffu + ((u >> 16) & 1u);   // RNE
  return (short)(u >> 16);
}
__device__ __forceinline__ float bf2f(short s) {
  return __uint_as_float(((unsigned)(unsigned short)s) << 16);
}

// async global->LDS, 16B/lane: lds dest = wave-uniform base + lane*16.
// Used ONLY in gemm_bt this round (R2-crash isolation).
__device__ __forceinline__ void gl2lds16(const short* g, short* l) {
  __builtin_amdgcn_global_load_lds(
      (const __attribute__((address_space(1))) u32*)g,
      (__attribute__((address_space(3))) u32*)l, 16, 0, 0);
}

// ---------------- cast fp32 -> bf16, x4 vectorized ----------------
__global__ __launch_bounds__(256) void cast_bf16_kernel(const float* __restrict__ in,
                                                        short* __restrict__ out, int n4) {
  int i = blockIdx.x * 256 + threadIdx.x;
  if (i >= n4) return;
  f32x4 f = ((const f32x4*)in)[i];
  short4v o;
  o[0] = f2bf(f[0]); o[1] = f2bf(f[1]); o[2] = f2bf(f[2]); o[3] = f2bf(f[3]);
  ((short4v*)out)[i] = o;
}

// ---------------- concat biases into cb1[3072], cb2[3072], cb3[4096] ----------------
__global__ __launch_bounds__(256) void concat_bias_kernel(
    const float* bkd, const float* bqd, const float* bkr,
    const float* bqu, const float* bqr, const float* bku, const float* bvu,
    float* cb1, float* cb2, float* cb3) {
  int idx = blockIdx.x * 256 + threadIdx.x;
  if (idx < 3072) {
    cb1[idx] = idx < 512 ? bkd[idx] : (idx < 2048 ? bqd[idx - 512] : bkr[idx - 2048]);
  } else if (idx < 6144) {
    int j = idx - 3072;
    cb2[j] = j < 2048 ? bqu[j] : bqr[j - 2048];
  } else if (idx < 10240) {
    int j = idx - 6144;
    cb3[j] = j < 2048 ? bku[j] : bvu[j - 2048];
  }
}

// ---------------- C[M,N] = A[M,K] @ B[N,K]^T + bias ----------------
// m97 structure: global_load_lds width-16 staging (linear LDS [row][32]),
// 2-barrier K-loop, 128x128 tile, BK=32, 4 waves (2x2 of 64x64).
// MODE 0: bf16 row-major.  MODE 1: f32 row-major.
// MODE 2: col<2048 scatter to qfull[B,H,S,192]; col>=2048 -> out2[row*1024+col-2048].
// MODE 3: col<2048 scatter to kfull[B,H,S,192]; col>=2048 -> out2[row*2048+col-2048].
template<int MODE>
__global__ __launch_bounds__(256) void gemm_bt(const short* __restrict__ A, int lda,
                                               const short* __restrict__ Bm, int ldb,
                                               const float* __restrict__ bias,
                                               void* __restrict__ Cout, void* __restrict__ out2,
                                               int M, int N, int K) {
  __shared__ __align__(16) short sA[128 * 32];
  __shared__ __align__(16) short sB[128 * 32];
  const int tid = threadIdx.x;
  const int w = tid >> 6, L = tid & 63, quad = L >> 4, lc = L & 15;
  const int wm = w >> 1, wn = w & 1;
  const int tm = blockIdx.x * 128, tn = blockIdx.y * 128;
  const int lrow = L >> 2, lch = (L & 3) * 8;
  f32x4 acc[4][4] = {};
  const int nk = K >> 5;
  for (int kt = 0; kt < nk; ++kt) {
    const int k0 = kt << 5;
    __syncthreads();
    // wave w stages 32 rows of A and B; 1 instr = 16 rows (64 lanes x 16B)
    {
      int sub = w * 2;
      gl2lds16(A + (size_t)(tm + sub * 16 + lrow) * lda + k0 + lch, &sA[sub * 512]);
      gl2lds16(A + (size_t)(tm + sub * 16 + 16 + lrow) * lda + k0 + lch, &sA[sub * 512 + 512]);
      gl2lds16(Bm + (size_t)(tn + sub * 16 + lrow) * ldb + k0 + lch, &sB[sub * 512]);
      gl2lds16(Bm + (size_t)(tn + sub * 16 + 16 + lrow) * ldb + k0 + lch, &sB[sub * 512 + 512]);
    }
    __syncthreads();  // compiler drains vmcnt before barrier -> LDS visible
    short8 af[4], bfr[4];
#pragma unroll
    for (int ms = 0; ms < 4; ++ms)
      af[ms] = *(const short8*)&sA[(wm * 64 + ms * 16 + lc) * 32 + quad * 8];
#pragma unroll
    for (int ns = 0; ns < 4; ++ns)
      bfr[ns] = *(const short8*)&sB[(wn * 64 + ns * 16 + lc) * 32 + quad * 8];
#pragma unroll
    for (int ms = 0; ms < 4; ++ms)
#pragma unroll
      for (int ns = 0; ns < 4; ++ns)
        acc[ms][ns] = __builtin_amdgcn_mfma_f32_16x16x32_bf16(af[ms], bfr[ns], acc[ms][ns], 0, 0, 0);
  }
  // epilogue: C row = quad*4+reg, col = lane&15 (verified m89/m91 layout)
#pragma unroll
  for (int ms = 0; ms < 4; ++ms) {
    int row = tm + wm * 64 + ms * 16 + quad * 4;
#pragma unroll
    for (int ns = 0; ns < 4; ++ns) {
      int col = tn + wn * 64 + ns * 16 + lc;
      float bv = bias[col];
#pragma unroll
      for (int r = 0; r < 4; ++r) {
        float vv = acc[ms][ns][r] + bv;
        int rrow = row + r;
        if (MODE == 0)      ((short*)Cout)[(size_t)rrow * N + col] = f2bf(vv);
        else if (MODE == 1) ((float*)Cout)[(size_t)rrow * N + col] = vv;
        else {
          if (col < 2048) {  // content -> full[B,H,S,192] (block-uniform branch)
            int b_ = rrow >> 11, s_ = rrow & 2047, h_ = col >> 7, d_ = col & 127;
            ((short*)Cout)[(((size_t)(b_ * HH + h_)) * SS + s_) * 192 + d_] = f2bf(vv);
          } else {
            int auxn = (MODE == 2) ? 1024 : 2048;
            ((short*)out2)[(size_t)rrow * auxn + (col - 2048)] = f2bf(vv);
          }
        }
      }
    }
  }
}

// ------------- RoPE (rotate-half) into full[...,128:192]; strided bf16 src -------------
__global__ __launch_bounds__(256) void rope_kernel(const short* __restrict__ rin,
                                                   int rstride, int roff,
                                                   short* __restrict__ full) {
  int idx = blockIdx.x * 256 + threadIdx.x;  // B*S*H*32 threads
  int i = idx & 31, h = (idx >> 5) & 15, s = (idx >> 9) & 2047, b = idx >> 20;
  const short* base = rin + ((size_t)(b * SS + s)) * rstride + roff + h * DRR;
  float t1 = bf2f(base[i]), t2 = bf2f(base[i + 32]);
  float invf = expf(-9.210340371976184f * (float)i * (1.0f / 32.0f));  // 10000^(-i/32)
  float ang = (float)s * invf;
  float c = cosf(ang), sn = sinf(ang);
  short* ob = full + (((size_t)(b * HH + h)) * SS + s) * 192 + 128;
  ob[i]      = f2bf(t1 * c - t2 * sn);
  ob[i + 32] = f2bf(t1 * sn + t2 * c);
}

// ------------- V [B,S,H*DH] -> Vt [B,H,DH,S] -------------
__global__ __launch_bounds__(256) void transpose_v_kernel(const short* __restrict__ v,
                                                          short* __restrict__ vt) {
  int idx = blockIdx.x * 256 + threadIdx.x;  // B*H*DH*S threads
  int s = idx & 2047, d = (idx >> 11) & 127, h = (idx >> 18) & 15, b = idx >> 22;
  vt[idx] = v[((size_t)(b * SS + s)) * 2048 + h * 128 + d];
}

__device__ __forceinline__ float quad_max(float v) {
  v = fmaxf(v, __shfl_xor(v, 1));
  v = fmaxf(v, __shfl_xor(v, 2));
  v = fmaxf(v, __shfl_xor(v, 4));
  v = fmaxf(v, __shfl_xor(v, 8));
  return v;
}
__device__ __forceinline__ float quad_sum(float v) {
  v += __shfl_xor(v, 1); v += __shfl_xor(v, 2);
  v += __shfl_xor(v, 4); v += __shfl_xor(v, 8);
  return v;
}

// ------------- flash attention (R3-proven body) -------------
// grid (16, B*H). qt = 15 - ((bx+by)&15): spreads heavy (qt=15) blocks across
// all 8 XCDs (plain 15-bx put every heavy block at linear id % 8 == 0 -> XCD0
// hot-spot, the R3 occupancy tail). K-tile staged into 48KB LDS (XOR swizzle);
// P (128x136) unioned over sK; 3 barriers/iter. NO register prefetch (R5's
// pf[12] spilled ~300MB scratch), NO launch_bounds cap >2 (R4's (256,3)
// forced VGPR=84 + spill).
__global__ __launch_bounds__(256, 2) void mla_flash_kernel(const short* __restrict__ Qf,
                                                           const short* __restrict__ Kf,
                                                           const short* __restrict__ Vt,
                                                           short* __restrict__ attn) {
  const int qt = 15 - (int)((blockIdx.x + blockIdx.y) & 15);
  const int bh = blockIdx.y, h = bh & 15, b = bh >> 4;
  const int tid = threadIdx.x, w = tid >> 6, L = tid & 63, quad = L >> 4, lc = L & 15;
  __shared__ __align__(16) short sK[6 * 128 * 32];  // 48KB; P unioned at offset 0
  short* Pf = sK;                                   // [128][136] bf16

  const short* Qb = Qf + ((size_t)bh) * SS * 192;
  const short* Kb = Kf + ((size_t)bh) * SS * 192;
  const short* Vb = Vt + ((size_t)bh) * DHH * SS;

  const int qrow0 = qt * 128 + w * 32;
  short8 qa[2][6];
#pragma unroll
  for (int ms = 0; ms < 2; ++ms)
#pragma unroll
    for (int kk = 0; kk < 6; ++kk)
      qa[ms][kk] = *(const short8*)(Qb + (size_t)(qrow0 + ms * 16 + lc) * 192 + kk * 32 + quad * 8);

  f32x4 O[2][8] = {};
  float mrow[2][4], lrow[2][4];
#pragma unroll
  for (int ms = 0; ms < 2; ++ms)
#pragma unroll
    for (int r = 0; r < 4; ++r) { mrow[ms][r] = -1e30f; lrow[ms][r] = 0.f; }

  for (int kt = 0; kt <= qt; ++kt) {
    __syncthreads();  // prior iter's P/sK LDS reads all done before overwrite
    // stage K-tile [kt*128, +128) x 192 into sK: 3072 16B chunks, 12/thread
#pragma unroll
    for (int i = 0; i < 12; ++i) {
      int idx = i * 256 + tid;
      int seg = idx >> 9, rem = idx & 511, row = rem >> 2, q = rem & 3;
      short8 v = *(const short8*)(Kb + (size_t)(kt * 128 + row) * 192 + seg * 32 + q * 8);
      int slot = row * 4 + (q ^ ((row >> 1) & 3));
      *(short8*)&sK[(seg * 512 + slot) * 8] = v;
    }
    __syncthreads();  // sK ready
    f32x4 sc[2][8] = {};
#pragma unroll
    for (int kk = 0; kk < 6; ++kk)
#pragma unroll
      for (int ns = 0; ns < 8; ++ns) {
        int rr = ns * 16 + lc;
        short8 kb = *(const short8*)&sK[(kk * 512 + rr * 4 + (quad ^ ((rr >> 1) & 3))) * 8];
        sc[0][ns] = __builtin_amdgcn_mfma_f32_16x16x32_bf16(qa[0][kk], kb, sc[0][ns], 0, 0, 0);
        sc[1][ns] = __builtin_amdgcn_mfma_f32_16x16x32_bf16(qa[1][kk], kb, sc[1][ns], 0, 0, 0);
      }
    const float scale = 0.07216878364870322f;  // 1/sqrt(192)
    const bool diag = (kt == qt);
#pragma unroll
    for (int ms = 0; ms < 2; ++ms)
#pragma unroll
      for (int ns = 0; ns < 8; ++ns)
#pragma unroll
        for (int r = 0; r < 4; ++r) {
          float vv = sc[ms][ns][r] * scale;
          if (diag && (ns * 16 + lc > w * 32 + ms * 16 + quad * 4 + r)) vv = -1e30f;
          sc[ms][ns][r] = vv;
        }
    // online softmax; row (ms, quad*4+r) lives in this quad's 16 lanes
#pragma unroll
    for (int ms = 0; ms < 2; ++ms)
#pragma unroll
      for (int r = 0; r < 4; ++r) {
        float mx = sc[ms][0][r];
#pragma unroll
        for (int ns = 1; ns < 8; ++ns) mx = fmaxf(mx, sc[ms][ns][r]);
        mx = quad_max(mx);
        float mnew = fmaxf(mrow[ms][r], mx);
        float alpha = __expf(mrow[ms][r] - mnew);
        mrow[ms][r] = mnew;
        float ps = 0.f;
#pragma unroll
        for (int ns = 0; ns < 8; ++ns) {
          float p = __expf(sc[ms][ns][r] - mnew);
          sc[ms][ns][r] = p;
          ps += p;
        }
        ps = quad_sum(ps);
        lrow[ms][r] = lrow[ms][r] * alpha + ps;
#pragma unroll
        for (int n = 0; n < 8; ++n) O[ms][n][r] *= alpha;
      }
    __syncthreads();  // all waves' QK sK-reads done before P overwrites region
    // P (bf16) C-layout -> LDS (wave-private rows; same-wave RAW via lgkmcnt)
#pragma unroll
    for (int ms = 0; ms < 2; ++ms)
#pragma unroll
      for (int ns = 0; ns < 8; ++ns)
#pragma unroll
        for (int r = 0; r < 4; ++r)
          Pf[(w * 32 + ms * 16 + quad * 4 + r) * 136 + ns * 16 + lc] = f2bf(sc[ms][ns][r]);
    // PV: A = P (own rows, A-layout), B = Vt
#pragma unroll
    for (int kk2 = 0; kk2 < 4; ++kk2) {
      short8 pa[2];
      pa[0] = *(const short8*)&Pf[(w * 32 + lc) * 136 + kk2 * 32 + quad * 8];
      pa[1] = *(const short8*)&Pf[(w * 32 + 16 + lc) * 136 + kk2 * 32 + quad * 8];
      short8 vb[8];
#pragma unroll
      for (int n = 0; n < 8; ++n)
        vb[n] = *(const short8*)(Vb + (size_t)(n * 16 + lc) * SS + kt * 128 + kk2 * 32 + quad * 8);
#pragma unroll
      for (int ms = 0; ms < 2; ++ms)
#pragma unroll
        for (int n = 0; n < 8; ++n)
          O[ms][n] = __builtin_amdgcn_mfma_f32_16x16x32_bf16(pa[ms], vb[n], O[ms][n], 0, 0, 0);
    }
  }
  // epilogue: O / l -> attn [B,S,H*DH] bf16
#pragma unroll
  for (int ms = 0; ms < 2; ++ms)
#pragma unroll
    for (int r = 0; r < 4; ++r) {
      float inv = 1.0f / lrow[ms][r];
      int srow = qt * 128 + w * 32 + ms * 16 + quad * 4 + r;
      short* dst = attn + ((size_t)b * SS + srow) * 2048 + h * 128;
#pragma unroll
      for (int n = 0; n < 8; ++n)
        dst[n * 16 + lc] = f2bf(O[ms][n][r] * inv);
    }
}

extern "C" void kernel_launch(void* const* d_in, const int* in_sizes, int n_in,
                              void* d_out, int out_size, void* d_ws, size_t ws_size,
                              hipStream_t stream) {
  const float* x   = (const float*)d_in[0];
  const float* Wkd = (const float*)d_in[1];
  const float* bkd = (const float*)d_in[2];
  const float* Wqd = (const float*)d_in[3];
  const float* bqd = (const float*)d_in[4];
  const float* Wku = (const float*)d_in[5];
  const float* bku = (const float*)d_in[6];
  const float* Wvu = (const float*)d_in[7];
  const float* bvu = (const float*)d_in[8];
  const float* Wqu = (const float*)d_in[9];
  const float* bqu = (const float*)d_in[10];
  const float* Wkr = (const float*)d_in[11];
  const float* bkr = (const float*)d_in[12];
  const float* Wqr = (const float*)d_in[13];
  const float* bqr = (const float*)d_in[14];
  const float* Wo  = (const float*)d_in[15];
  const float* bo  = (const float*)d_in[16];

  char* ws = (char*)d_ws;
  size_t off = 0;
  auto alloc = [&](size_t elems, size_t esz) -> void* {
    void* p = (void*)(ws + off);
    off += elems * esz;
    off = (off + 255) & ~(size_t)255;
    return p;
  };
  const int MS = BB * SS;  // 4096
  short* xb    = (short*)alloc((size_t)MS * DD, 2);
  short* cbuf  = (short*)alloc((size_t)MS * 3072, 2);   // kvc | qc | k_r
  short* qrbuf = (short*)alloc((size_t)MS * 1024, 2);
  short* vbuf  = (short*)alloc((size_t)MS * 2048, 2);
  short* w1    = (short*)alloc((size_t)3072 * 2048, 2);  // [Wkd;Wqd;Wkr]
  short* w2    = (short*)alloc((size_t)3072 * 1536, 2);  // [Wqu;Wqr]
  short* w3    = (short*)alloc((size_t)4096 * 512, 2);   // [Wku;Wvu]
  short* wob   = (short*)alloc((size_t)2048 * 2048, 2);
  float* cb1   = (float*)alloc(3072, 4);
  float* cb2   = (float*)alloc(3072, 4);
  float* cb3   = (float*)alloc(4096, 4);
  short* qfull = (short*)alloc((size_t)BB * HH * SS * 192, 2);
  short* kfull = (short*)alloc((size_t)BB * HH * SS * 192, 2);
  short* vt    = (short*)alloc((size_t)BB * HH * DHH * SS, 2);
  short* attn  = (short*)alloc((size_t)MS * 2048, 2);
  if (off > ws_size) return;  // workspace too small: fail visibly

  auto cast = [&](const float* src, short* dst, size_t n) {
    int n4 = (int)(n >> 2);
    cast_bf16_kernel<<<dim3((unsigned)((n4 + 255) / 256)), dim3(256), 0, stream>>>(src, dst, n4);
  };
  cast(x,   xb, (size_t)MS * DD);
  cast(Wkd, w1,                          (size_t)512 * 2048);
  cast(Wqd, w1 + (size_t)512 * 2048,     (size_t)1536 * 2048);
  cast(Wkr, w1 + (size_t)2048 * 2048,    (size_t)1024 * 2048);
  cast(Wqu, w2,                          (size_t)2048 * 1536);
  cast(Wqr, w2 + (size_t)2048 * 1536,    (size_t)1024 * 1536);
  cast(Wku, w3,                          (size_t)2048 * 512);
  cast(Wvu, w3 + (size_t)2048 * 512,     (size_t)2048 * 512);
  cast(Wo,  wob,                         (size_t)2048 * 2048);
  concat_bias_kernel<<<dim3(40), dim3(256), 0, stream>>>(bkd, bqd, bkr, bqu, bqr, bku, bvu,
                                                         cb1, cb2, cb3);

  dim3 blk(256);
  // GEMM1: x @ [Wkd;Wqd;Wkr]^T -> cbuf [4096 x 3072] (kvc | qc | k_r)
  gemm_bt<0><<<dim3(32, 24), blk, 0, stream>>>(xb, DD, w1, DD, cb1, cbuf, nullptr,
                                               MS, 3072, DD);
  // GEMM2: qc @ [Wqu;Wqr]^T -> q_cnt scattered to qfull + q_r -> qrbuf
  gemm_bt<2><<<dim3(32, 24), blk, 0, stream>>>(cbuf + 512, 3072, w2, DCQ, cb2, qfull, qrbuf,
                                               MS, 3072, DCQ);
  // GEMM3: kvc @ [Wku;Wvu]^T -> k_cnt scattered to kfull + v -> vbuf
  gemm_bt<3><<<dim3(32, 32), blk, 0, stream>>>(cbuf, 3072, w3, DCKV, cb3, kfull, vbuf,
                                               MS, 4096, DCKV);

  rope_kernel<<<dim3(BB * SS * HH * 32 / 256), blk, 0, stream>>>(qrbuf, 1024, 0, qfull);
  rope_kernel<<<dim3(BB * SS * HH * 32 / 256), blk, 0, stream>>>(cbuf, 3072, 2048, kfull);
  transpose_v_kernel<<<dim3(BB * HH * DHH * SS / 256), blk, 0, stream>>>(vbuf, vt);

  mla_flash_kernel<<<dim3(16, BB * HH), blk, 0, stream>>>(qfull, kfull, vt, attn);

  gemm_bt<1><<<dim3(32, 16), blk, 0, stream>>>(attn, DD, wob, DD, bo, d_out, nullptr,
                                               MS, DD, DD);
}